// Round 10
// baseline (144.691 us; speedup 1.0000x reference)
//
#include <hip/hip_runtime.h>
#include <hip/hip_bf16.h>

typedef __attribute__((ext_vector_type(8))) short short8;
typedef __attribute__((ext_vector_type(4))) float float4v;

#define LOG2E 1.44269504088896340736f

__device__ __forceinline__ unsigned short f2bf(float f) {
    unsigned int u = __float_as_uint(f);
    unsigned int r = (u + 0x7fffu + ((u >> 16) & 1u)) >> 16;  // RNE
    return (unsigned short)r;
}

// ---------------------------------------------------------------------------
// Kernel 1: convert Wk|Wq|Wv (fp32) -> combined bf16 Wb[192][1024]
// ---------------------------------------------------------------------------
__global__ void wconv_kernel(const float* __restrict__ Wk, const float* __restrict__ Wq,
                             const float* __restrict__ Wv, unsigned short* __restrict__ Wb) {
    int i = blockIdx.x * 256 + threadIdx.x;
    if (i >= 192 * 1024) return;
    float v;
    if (i < 65536)       v = Wk[i];
    else if (i < 131072) v = Wq[i - 65536];
    else                 v = Wv[i - 131072];
    Wb[i] = f2bf(v);
}

// ---------------------------------------------------------------------------
// Kernel 2: projection GEMM — round-21: M=64 TILE (B amortized 2x).
// R20 CONFIRMED the line-request model (proj 40->32us, predicted 25-32):
// duration tracks unique-cache-line requests (~22-25ns/line/CU). Remaining
// budget at M=32: B=192 lines/block-iter (24KB re-fetched by EVERY block,
// 192MB L2), A=64. This round: M=64, grid 256 (1 block/CU), 512 thr
// (8 waves = 2/SIMD, same TLP as proven config). Per-output requests
// x0.62 (320 lines per 64 rows vs 256 per 32); B L2 traffic halves.
// Wave map: rg=wave&3 (4 row-groups of 16), g=wave>>2 (2 n-groups of 6);
// inner loop shape identical to R20 (6 acc, 6 MFMA/kc).
// Staging = R20's verified patterns re-parameterized:
//   B: 8 waves x 3 regions (lane->row l>>3, chunk l&7, LDS chunk XOR'd)
//   A: 512 threads -> 64 rows (thread t -> row t>>3, colgroup t&7, 32B
//      contiguous), f2bf at stage time, XOR chunk on write.
// Counted-vmcnt ledger (issue order [3 B][2 A], pinned):
//   end-of-iter queue = A(kt+1)2 B(kt+1)3 A(kt+2)2; vmcnt(2) drains
//   B(kt+1)+A(kt+1) for the ds_writes, leaves A(kt+2) flying.
//   kt==14 -> vmcnt(0) (no A(16) issued). Single barrier per iter.
// WAR: writes target buf (kt+1)&1, last read at iter kt-1 before its
// barrier. aS sets statically indexed under full unroll (rule #20).
// ---------------------------------------------------------------------------
__global__ __launch_bounds__(512) void proj_kernel(
    const float* __restrict__ x, const unsigned short* __restrict__ Wb,
    unsigned short* __restrict__ qs, unsigned short* __restrict__ ks,
    unsigned short* __restrict__ vT) {
    __shared__ unsigned short Bl[2][12288];  // 2 x 192 rows x 64 ushort, 48 KB
    __shared__ unsigned short Al[2][4096];   // 2 x 64 rows x 64 ushort, 16 KB

    const int tid  = threadIdx.x;
    const int lane = tid & 63;
    const int wave = tid >> 6;   // 0..7
    const int rg   = wave & 3;   // row group (A read): 4 x 16 rows
    const int g    = wave >> 2;  // n-tile group: 2 x 6 n-tiles
    const int quad = lane >> 4;
    const int l16  = lane & 15;
    const int t0   = blockIdx.x * 64;

    // B staging: wave covers regions wave*3..+2 (24 regions = 192 rows);
    // lane l -> (row l>>3, source chunk l&7), LDS chunk (l&7)^(l>>3).
    const int brow_in = lane >> 3;
    const int bchunk  = lane & 7;
    const int bwchunk = bchunk ^ brow_in;

    // A staging (block-cooperative, coalesced): thread t -> row t>>3 (0..63),
    // colgroup t&7 (8 floats = 32B contiguous). LDS chunk (t&7)^(row&7).
    const int ar = tid >> 3;
    const int ak = tid & 7;
    const float* xsrc = x + (size_t)(t0 + ar) * 1024 + ak * 8;
    const int awoff = ar * 64 + ((ak ^ (ar & 7)) * 8);

    const int arow = rg * 16 + l16;   // A fragment read row (0..63)
    const int swz  = l16 & 7;

    float4v acc[6];
#pragma unroll
    for (int n = 0; n < 6; n++) acc[n] = (float4v){0.f, 0.f, 0.f, 0.f};

#define STAGE_LOAD_B(REG, KN)                                                     \
    {                                                                             \
        _Pragma("unroll")                                                         \
        for (int i = 0; i < 3; i++) {                                             \
            const int rowg = (wave * 3 + i) * 8 + brow_in;                        \
            REG[i] = *(const short8*)(Wb + (size_t)rowg * 1024 + (KN) + bchunk * 8); \
        }                                                                         \
    }

#define STAGE_WRITE_B(BUF, REG)                                                   \
    {                                                                             \
        _Pragma("unroll")                                                         \
        for (int i = 0; i < 3; i++)                                               \
            *(short8*)&Bl[BUF][(wave * 3 + i) * 512 + brow_in * 64 + bwchunk * 8] = REG[i]; \
    }

#define LOAD_A_G(F0, F1, KN)                              \
    {                                                     \
        F0 = *(const float4v*)(xsrc + (KN));              \
        F1 = *(const float4v*)(xsrc + (KN) + 4);          \
    }

#define STAGE_WRITE_A(BUF, F0, F1)                        \
    {                                                     \
        short8 w;                                         \
        _Pragma("unroll")                                 \
        for (int j = 0; j < 4; j++) {                     \
            w[j]     = (short)f2bf(F0[j]);                \
            w[4 + j] = (short)f2bf(F1[j]);                \
        }                                                 \
        *(short8*)&Al[BUF][awoff] = w;                    \
    }

    // prologue — issue order: B(0)[3], A(0)[2], A(1)[2]; vmcnt(2) drains
    // B(0)+A(0), leaves A(1) flying; write buf0; barrier.
    short8 breg[3];
    float4v aS[2][2];
    float4v a0f0, a0f1;
    STAGE_LOAD_B(breg, 0)
    asm volatile("" ::: "memory");
    LOAD_A_G(a0f0, a0f1, 0)
    asm volatile("" ::: "memory");
    LOAD_A_G(aS[1][0], aS[1][1], 64)
    asm volatile("s_waitcnt vmcnt(2)" ::: "memory");
    STAGE_WRITE_B(0, breg)
    STAGE_WRITE_A(0, a0f0, a0f1)
    asm volatile("s_waitcnt lgkmcnt(0)" ::: "memory");
    __builtin_amdgcn_s_barrier();

#pragma unroll
    for (int kt = 0; kt < 16; kt++) {
        __builtin_amdgcn_sched_barrier(0);
        // issue next B tile then A(kt+2) (oldest-first in vm queue)
        if (kt < 15) {
            STAGE_LOAD_B(breg, (kt + 1) * 64)
        }
        asm volatile("" ::: "memory");  // pin: B-loads before A-loads
        if (kt < 14) {
            LOAD_A_G(aS[kt & 1][0], aS[kt & 1][1], (kt + 2) * 64)
        }
        asm volatile("" ::: "memory");  // close vm issue group

        // compute tile kt from buf kt&1 (A and B both from LDS)
        const unsigned short* Bc = Bl[kt & 1];
        const unsigned short* Ac = Al[kt & 1];
#pragma unroll
        for (int kc = 0; kc < 2; kc++) {
            const int coff = ((kc * 4 + quad) ^ swz) * 8;
            const short8 af = *(const short8*)&Ac[arow * 64 + coff];
#pragma unroll
            for (int n = 0; n < 6; n++) {
                const int row = (g * 6 + n) * 16 + l16;
                const short8 bf = *(const short8*)&Bc[row * 64 + coff];
                acc[n] = __builtin_amdgcn_mfma_f32_16x16x32_bf16(af, bf, acc[n], 0, 0, 0);
            }
        }

        if (kt < 15) {
            // drain A(kt+1)+B(kt+1) for the ds_writes; keep A(kt+2) flying.
            if (kt < 14) {
                asm volatile("s_waitcnt vmcnt(2)" ::: "memory");
            } else {
                asm volatile("s_waitcnt vmcnt(0)" ::: "memory");
            }
            STAGE_WRITE_B((kt + 1) & 1, breg)
            STAGE_WRITE_A((kt + 1) & 1, aS[(kt + 1) & 1][0], aS[(kt + 1) & 1][1])
            asm volatile("s_waitcnt lgkmcnt(0)" ::: "memory");
            __builtin_amdgcn_s_barrier();
        }
    }
#undef STAGE_LOAD_B
#undef STAGE_WRITE_B
#undef LOAD_A_G
#undef STAGE_WRITE_A

    // Epilogue. C layout: row = quad*4 + r, col = l16.
    // n-tile mt = g*6+nn: 0-3 -> ks, 4-7 -> qs (x0.125), 8-11 -> vT.
    const int rowD = t0 + rg * 16 + quad * 4;
#pragma unroll
    for (int nn = 0; nn < 6; nn++) {
        const int mt = g * 6 + nn;
#pragma unroll
        for (int r = 0; r < 4; r++) {
            const int t = rowD + r;
            const float val = acc[nn][r];
            if (mt < 4) {
                ks[(size_t)t * 64 + mt * 16 + l16] = f2bf(val);
            } else if (mt < 8) {
                qs[(size_t)t * 64 + (mt - 4) * 16 + l16] = f2bf(val * 0.125f);
            } else {
                const int b = t >> 11, tt = t & 2047;
                vT[(size_t)b * 131072 + (size_t)((mt - 8) * 16 + l16) * 2048 + tt] = f2bf(val);
            }
        }
    }
}

// ---------------------------------------------------------------------------
// Kernel 3: causal attention v3 — R11 verbatim (best measured: ~33us)
// ---------------------------------------------------------------------------
__global__ __launch_bounds__(256) void attn_kernel(
    const unsigned short* __restrict__ qs, const unsigned short* __restrict__ ks,
    const unsigned short* __restrict__ vT, float* __restrict__ out) {
    __shared__ unsigned short Kl[4 * 64 * 72];
    __shared__ unsigned short Vl[64 * 264];
    __shared__ unsigned short P[4][16 * 72];
    __shared__ float Ll[4][16];
    float* Of = (float*)Kl;  // merge buffer aliases Kl: [4][16][68] fp32

    const int tid  = threadIdx.x;
    const int lane = tid & 63;
    const int wave = tid >> 6;
    const int quad = lane >> 4;
    const int l16  = lane & 15;
    const int bx   = blockIdx.x;
    const int b    = bx & 7;
    const int i    = bx >> 3;
    const int qt   = (i & 1) ? (127 - (i >> 1)) : (i >> 1);
    const int t0   = qt * 16;

    const unsigned short* qb = qs + (size_t)b * 131072;
    const unsigned short* kb = ks + (size_t)b * 131072;
    const unsigned short* vb = vT + (size_t)b * 131072;

    const int ksr = tid >> 3;
    const int ksc = (tid & 7) * 8;
    const int vsr = tid >> 5;
    const int vsc = (tid & 31) * 8;

    const int qrow = t0 + l16;
    const short8 qf0 = *(const short8*)(qb + (size_t)qrow * 64 + quad * 8);
    const short8 qf1 = *(const short8*)(qb + (size_t)qrow * 64 + 32 + quad * 8);

    float4v o[4];
#pragma unroll
    for (int ot = 0; ot < 4; ot++) o[ot] = (float4v){0.f, 0.f, 0.f, 0.f};
    float lpart = 0.f;

    const int nkb  = (qt >> 2) + 1;
    const int nsup = (nkb + 3) >> 2;

    for (int s = 0; s < nsup; s++) {
        const int key0 = s * 256;
        __syncthreads();
#pragma unroll
        for (int i2 = 0; i2 < 8; i2++) {
            int kr = key0 + i2 * 32 + ksr; kr = kr < 2047 ? kr : 2047;
            *(short8*)&Kl[(i2 * 32 + ksr) * 72 + ksc] = *(const short8*)(kb + (size_t)kr * 64 + ksc);
        }
#pragma unroll
        for (int i2 = 0; i2 < 8; i2++) {
            const int orow = i2 * 8 + vsr;
            int kc2 = key0 + vsc; kc2 = kc2 < 2040 ? kc2 : 2040;
            *(short8*)&Vl[orow * 264 + vsc] = *(const short8*)(vb + (size_t)orow * 2048 + kc2);
        }
        __syncthreads();

        const int jt = s * 4 + wave;
        if (jt < nkb) {
            const int kbase = wave * 64;
            float4v sv[4];
#pragma unroll
            for (int kt = 0; kt < 4; kt++) {
                const short8 ka = *(const short8*)&Kl[(kbase + kt * 16 + l16) * 72 + quad * 8];
                const short8 kc = *(const short8*)&Kl[(kbase + kt * 16 + l16) * 72 + 32 + quad * 8];
                float4v z = (float4v){0.f, 0.f, 0.f, 0.f};
                z = __builtin_amdgcn_mfma_f32_16x16x32_bf16(ka, qf0, z, 0, 0, 0);
                sv[kt] = __builtin_amdgcn_mfma_f32_16x16x32_bf16(kc, qf1, z, 0, 0, 0);
            }
            if (jt == nkb - 1) {
#pragma unroll
                for (int kt = 0; kt < 4; kt++)
#pragma unroll
                    for (int r = 0; r < 4; r++)
                        if (jt * 64 + kt * 16 + quad * 4 + r > qrow) sv[kt][r] = -1e30f;
            }
#pragma unroll
            for (int kt = 0; kt < 4; kt++) {
                float p0 = exp2f(sv[kt][0] * LOG2E);
                float p1 = exp2f(sv[kt][1] * LOG2E);
                float p2 = exp2f(sv[kt][2] * LOG2E);
                float p3 = exp2f(sv[kt][3] * LOG2E);
                lpart += (p0 + p1) + (p2 + p3);
                unsigned int lo = (unsigned int)f2bf(p0) | ((unsigned int)f2bf(p1) << 16);
                unsigned int hi = (unsigned int)f2bf(p2) | ((unsigned int)f2bf(p3) << 16);
                unsigned long long w = ((unsigned long long)hi << 32) | lo;
                *(unsigned long long*)&P[wave][l16 * 72 + kt * 16 + quad * 4] = w;
            }
#pragma unroll
            for (int kc = 0; kc < 2; kc++) {
                const short8 pf = *(const short8*)&P[wave][l16 * 72 + kc * 32 + quad * 8];
#pragma unroll
                for (int ot = 0; ot < 4; ot++) {
                    const short8 vf = *(const short8*)&Vl[(ot * 16 + l16) * 264 + wave * 64 + kc * 32 + quad * 8];
                    o[ot] = __builtin_amdgcn_mfma_f32_16x16x32_bf16(pf, vf, o[ot], 0, 0, 0);
                }
            }
        }
    }

    lpart += __shfl_xor(lpart, 16);
    lpart += __shfl_xor(lpart, 32);
    __syncthreads();
#pragma unroll
    for (int r = 0; r < 4; r++)
#pragma unroll
        for (int ot = 0; ot < 4; ot++)
            Of[wave * 1088 + (quad * 4 + r) * 68 + ot * 16 + l16] = o[ot][r];
    if (lane < 16) Ll[wave][lane] = lpart;
    __syncthreads();

    {
        const int row = tid >> 4;
        const int c0  = (tid & 15) * 4;
        const float lsum = Ll[0][row] + Ll[1][row] + Ll[2][row] + Ll[3][row];
        float4v v0 = *(const float4v*)&Of[0 * 1088 + row * 68 + c0];
        float4v v1 = *(const float4v*)&Of[1 * 1088 + row * 68 + c0];
        float4v v2 = *(const float4v*)&Of[2 * 1088 + row * 68 + c0];
        float4v v3 = *(const float4v*)&Of[3 * 1088 + row * 68 + c0];
        float4v res;
        const float inv = 1.0f / lsum;
#pragma unroll
        for (int j = 0; j < 4; j++)
            res[j] = ((v0[j] + v1[j]) + (v2[j] + v3[j])) * inv;
        float* ob = out + (size_t)b * 131072 + (size_t)(t0 + row) * 64 + c0;
        *(float4v*)ob = res;
    }
}

// ---------------------------------------------------------------------------
extern "C" void kernel_launch(void* const* d_in, const int* in_sizes, int n_in,
                              void* d_out, int out_size, void* d_ws, size_t ws_size,
                              hipStream_t stream) {
    const float* x  = (const float*)d_in[0];
    const float* Wk = (const float*)d_in[1];
    const float* Wq = (const float*)d_in[2];
    const float* Wv = (const float*)d_in[3];
    float* out = (float*)d_out;

    // Workspace: Wb 384 KB (+pad) | qs 2 MB | ks 2 MB | vT 2 MB
    unsigned short* Wb  = (unsigned short*)d_ws;
    unsigned short* qsb = (unsigned short*)((char*)d_ws + 393216);
    unsigned short* ksb = qsb + 1048576;
    unsigned short* vTb = ksb + 1048576;

    hipLaunchKernelGGL(wconv_kernel, dim3(768), dim3(256), 0, stream, Wk, Wq, Wv, Wb);
    hipLaunchKernelGGL(proj_kernel, dim3(256), dim3(512), 0, stream, x, Wb, qsb, ksb, vTb);
    hipLaunchKernelGGL(attn_kernel, dim3(1024), dim3(256), 0, stream, qsb, ksb, vTb, out);
}

// Round 11
// 134.452 us; speedup vs baseline: 1.0761x; 1.0761x over previous
//
#include <hip/hip_runtime.h>
#include <hip/hip_bf16.h>

typedef __attribute__((ext_vector_type(8))) short short8;
typedef __attribute__((ext_vector_type(4))) float float4v;

#define LOG2E 1.44269504088896340736f

__device__ __forceinline__ unsigned short f2bf(float f) {
    unsigned int u = __float_as_uint(f);
    unsigned int r = (u + 0x7fffu + ((u >> 16) & 1u)) >> 16;  // RNE
    return (unsigned short)r;
}

// ---------------------------------------------------------------------------
// Kernel 1: convert Wk|Wq|Wv (fp32) -> combined bf16 Wb[192][1024]
// ---------------------------------------------------------------------------
__global__ void wconv_kernel(const float* __restrict__ Wk, const float* __restrict__ Wq,
                             const float* __restrict__ Wv, unsigned short* __restrict__ Wb) {
    int i = blockIdx.x * 256 + threadIdx.x;
    if (i >= 192 * 1024) return;
    float v;
    if (i < 65536)       v = Wk[i];
    else if (i < 131072) v = Wq[i - 65536];
    else                 v = Wv[i - 131072];
    Wb[i] = f2bf(v);
}

// ---------------------------------------------------------------------------
// Kernel 2: projection GEMM — R20 verbatim (best measured: proj ~32us,
// total 142.35). R21's M=64 (1 block/CU) regressed: lost the 2-block
// barrier-gap overlap. M=32, grid 512, coalesced-A via LDS, no DMA.
// ---------------------------------------------------------------------------
__global__ __launch_bounds__(256) void proj_kernel(
    const float* __restrict__ x, const unsigned short* __restrict__ Wb,
    unsigned short* __restrict__ qs, unsigned short* __restrict__ ks,
    unsigned short* __restrict__ vT) {
    __shared__ unsigned short Bl[2][12288];  // 2 x 192 rows x 64 ushort, 48 KB
    __shared__ unsigned short Al[2][2048];   // 2 x 32 rows x 64 ushort, 8 KB

    const int tid  = threadIdx.x;
    const int lane = tid & 63;
    const int wave = tid >> 6;
    const int rg   = wave & 1;   // row group (A read)
    const int g    = wave >> 1;  // n-tile group
    const int quad = lane >> 4;
    const int l16  = lane & 15;
    const int t0   = blockIdx.x * 32;

    const int brow_in = lane >> 3;
    const int bchunk  = lane & 7;
    const int bwchunk = bchunk ^ brow_in;

    const int ar = tid >> 3;
    const int ak = tid & 7;
    const float* xsrc = x + (size_t)(t0 + ar) * 1024 + ak * 8;
    const int awoff = ar * 64 + ((ak ^ (ar & 7)) * 8);

    const int arow = rg * 16 + l16;
    const int swz  = l16 & 7;

    float4v acc[6];
#pragma unroll
    for (int n = 0; n < 6; n++) acc[n] = (float4v){0.f, 0.f, 0.f, 0.f};

#define STAGE_LOAD_B(REG, KN)                                                     \
    {                                                                             \
        _Pragma("unroll")                                                         \
        for (int i = 0; i < 6; i++) {                                             \
            const int rowg = (wave * 6 + i) * 8 + brow_in;                        \
            REG[i] = *(const short8*)(Wb + (size_t)rowg * 1024 + (KN) + bchunk * 8); \
        }                                                                         \
    }

#define STAGE_WRITE_B(BUF, REG)                                                   \
    {                                                                             \
        _Pragma("unroll")                                                         \
        for (int i = 0; i < 6; i++)                                               \
            *(short8*)&Bl[BUF][(wave * 6 + i) * 512 + brow_in * 64 + bwchunk * 8] = REG[i]; \
    }

#define LOAD_A_G(F0, F1, KN)                              \
    {                                                     \
        F0 = *(const float4v*)(xsrc + (KN));              \
        F1 = *(const float4v*)(xsrc + (KN) + 4);          \
    }

#define STAGE_WRITE_A(BUF, F0, F1)                        \
    {                                                     \
        short8 w;                                         \
        _Pragma("unroll")                                 \
        for (int j = 0; j < 4; j++) {                     \
            w[j]     = (short)f2bf(F0[j]);                \
            w[4 + j] = (short)f2bf(F1[j]);                \
        }                                                 \
        *(short8*)&Al[BUF][awoff] = w;                    \
    }

    short8 breg[6];
    float4v aS[2][2];
    float4v a0f0, a0f1;
    STAGE_LOAD_B(breg, 0)
    asm volatile("" ::: "memory");
    LOAD_A_G(a0f0, a0f1, 0)
    asm volatile("" ::: "memory");
    LOAD_A_G(aS[1][0], aS[1][1], 64)
    asm volatile("s_waitcnt vmcnt(2)" ::: "memory");
    STAGE_WRITE_B(0, breg)
    STAGE_WRITE_A(0, a0f0, a0f1)
    asm volatile("s_waitcnt lgkmcnt(0)" ::: "memory");
    __builtin_amdgcn_s_barrier();

#pragma unroll
    for (int kt = 0; kt < 16; kt++) {
        __builtin_amdgcn_sched_barrier(0);
        if (kt < 15) {
            STAGE_LOAD_B(breg, (kt + 1) * 64)
        }
        asm volatile("" ::: "memory");
        if (kt < 14) {
            LOAD_A_G(aS[kt & 1][0], aS[kt & 1][1], (kt + 2) * 64)
        }
        asm volatile("" ::: "memory");

        const unsigned short* Bc = Bl[kt & 1];
        const unsigned short* Ac = Al[kt & 1];
#pragma unroll
        for (int kc = 0; kc < 2; kc++) {
            const int coff = ((kc * 4 + quad) ^ swz) * 8;
            const short8 af = *(const short8*)&Ac[arow * 64 + coff];
#pragma unroll
            for (int n = 0; n < 6; n++) {
                const int row = (g * 6 + n) * 16 + l16;
                const short8 bf = *(const short8*)&Bc[row * 64 + coff];
                acc[n] = __builtin_amdgcn_mfma_f32_16x16x32_bf16(af, bf, acc[n], 0, 0, 0);
            }
        }

        if (kt < 15) {
            if (kt < 14) {
                asm volatile("s_waitcnt vmcnt(2)" ::: "memory");
            } else {
                asm volatile("s_waitcnt vmcnt(0)" ::: "memory");
            }
            STAGE_WRITE_B((kt + 1) & 1, breg)
            STAGE_WRITE_A((kt + 1) & 1, aS[(kt + 1) & 1][0], aS[(kt + 1) & 1][1])
            asm volatile("s_waitcnt lgkmcnt(0)" ::: "memory");
            __builtin_amdgcn_s_barrier();
        }
    }
#undef STAGE_LOAD_B
#undef STAGE_WRITE_B
#undef LOAD_A_G
#undef STAGE_WRITE_A

    const int rowD = t0 + rg * 16 + quad * 4;
#pragma unroll
    for (int r = 0; r < 4; r++) {
        const int t = rowD + r;
        const int b = t >> 11, tt = t & 2047;
        if (g == 0) {
#pragma unroll
            for (int n = 0; n < 4; n++)
                ks[(size_t)t * 64 + n * 16 + l16] = f2bf(acc[n][r]);
#pragma unroll
            for (int n = 4; n < 6; n++)
                qs[(size_t)t * 64 + (n - 4) * 16 + l16] = f2bf(acc[n][r] * 0.125f);
        } else {
#pragma unroll
            for (int n = 0; n < 2; n++)
                qs[(size_t)t * 64 + (n + 2) * 16 + l16] = f2bf(acc[n][r] * 0.125f);
#pragma unroll
            for (int n = 2; n < 6; n++)
                vT[(size_t)b * 131072 + (size_t)((n - 2) * 16 + l16) * 2048 + tt] = f2bf(acc[n][r]);
        }
    }
}

// ---------------------------------------------------------------------------
// Kernel 3: causal attention v5 — QBLK=32: line-request amortization (the
// R20-confirmed model applied to attn). Old: 16 q-rows/block, 4 waves split
// keys; per batch Sum(nsup)=576 super-iters x 768 lines staged. New: 32
// q-rows/block (2 q-tiles), wave w -> (qsub=w&1 own q-tile, khalf=w>>1 key
// half); each wave computes 2 key-blocks/super-iter (FLOPs unchanged).
// Per-batch super-iters 576->288: staging requests AND barriers halve.
// Staging code byte-identical. Grid 512 = 2 blocks/CU (keeps the overlap
// R21 lost at 1 block/CU). Merge pairwise (waves w, w+2 share qsub), each
// thread writes 2 output rows. Causal skip per wave: nkb_w =
// ((2qt+qsub)>>2)+1; mask formula unchanged.
// ---------------------------------------------------------------------------
__global__ __launch_bounds__(256) void attn_kernel(
    const unsigned short* __restrict__ qs, const unsigned short* __restrict__ ks,
    const unsigned short* __restrict__ vT, float* __restrict__ out) {
    __shared__ unsigned short Kl[4 * 64 * 72];
    __shared__ unsigned short Vl[64 * 264];
    __shared__ unsigned short P[4][16 * 72];
    __shared__ float Ll[4][16];
    float* Of = (float*)Kl;  // merge buffer aliases Kl: [4][16][68] fp32

    const int tid  = threadIdx.x;
    const int lane = tid & 63;
    const int wave = tid >> 6;
    const int quad = lane >> 4;
    const int l16  = lane & 15;
    const int bx   = blockIdx.x;
    const int b    = bx & 7;
    const int i    = bx >> 3;                       // 0..63
    const int qt   = (i & 1) ? (63 - (i >> 1)) : (i >> 1);
    const int t0   = qt * 32;

    const int qsub  = wave & 1;   // which 16-row q-tile this wave owns
    const int khalf = wave >> 1;  // which half of the 4 key-blocks/super-iter

    const unsigned short* qb = qs + (size_t)b * 131072;
    const unsigned short* kb = ks + (size_t)b * 131072;
    const unsigned short* vb = vT + (size_t)b * 131072;

    const int ksr = tid >> 3;
    const int ksc = (tid & 7) * 8;
    const int vsr = tid >> 5;
    const int vsc = (tid & 31) * 8;

    const int qrow = t0 + qsub * 16 + l16;
    const short8 qf0 = *(const short8*)(qb + (size_t)qrow * 64 + quad * 8);
    const short8 qf1 = *(const short8*)(qb + (size_t)qrow * 64 + 32 + quad * 8);

    float4v o[4];
#pragma unroll
    for (int ot = 0; ot < 4; ot++) o[ot] = (float4v){0.f, 0.f, 0.f, 0.f};
    float lpart = 0.f;

    const int nkb   = (qt >> 1) + 1;                    // 64-key blocks, whole block
    const int nkb_w = ((2 * qt + qsub) >> 2) + 1;       // this wave's causal limit
    const int nsup  = (nkb + 3) >> 2;

    for (int s = 0; s < nsup; s++) {
        const int key0 = s * 256;
        __syncthreads();
#pragma unroll
        for (int i2 = 0; i2 < 8; i2++) {
            int kr = key0 + i2 * 32 + ksr; kr = kr < 2047 ? kr : 2047;
            *(short8*)&Kl[(i2 * 32 + ksr) * 72 + ksc] = *(const short8*)(kb + (size_t)kr * 64 + ksc);
        }
#pragma unroll
        for (int i2 = 0; i2 < 8; i2++) {
            const int orow = i2 * 8 + vsr;
            int kc2 = key0 + vsc; kc2 = kc2 < 2040 ? kc2 : 2040;
            *(short8*)&Vl[orow * 264 + vsc] = *(const short8*)(vb + (size_t)orow * 2048 + kc2);
        }
        __syncthreads();

#pragma unroll
        for (int kk = 0; kk < 2; kk++) {
            const int jt = s * 4 + khalf * 2 + kk;
            if (jt < nkb_w) {
                const int kbase = (khalf * 2 + kk) * 64;   // offset in staged 256
                float4v sv[4];
#pragma unroll
                for (int kt = 0; kt < 4; kt++) {
                    const short8 ka = *(const short8*)&Kl[(kbase + kt * 16 + l16) * 72 + quad * 8];
                    const short8 kc = *(const short8*)&Kl[(kbase + kt * 16 + l16) * 72 + 32 + quad * 8];
                    float4v z = (float4v){0.f, 0.f, 0.f, 0.f};
                    z = __builtin_amdgcn_mfma_f32_16x16x32_bf16(ka, qf0, z, 0, 0, 0);
                    sv[kt] = __builtin_amdgcn_mfma_f32_16x16x32_bf16(kc, qf1, z, 0, 0, 0);
                }
                if (jt == nkb_w - 1) {
#pragma unroll
                    for (int kt = 0; kt < 4; kt++)
#pragma unroll
                        for (int r = 0; r < 4; r++)
                            if (jt * 64 + kt * 16 + quad * 4 + r > qrow) sv[kt][r] = -1e30f;
                }
#pragma unroll
                for (int kt = 0; kt < 4; kt++) {
                    float p0 = exp2f(sv[kt][0] * LOG2E);
                    float p1 = exp2f(sv[kt][1] * LOG2E);
                    float p2 = exp2f(sv[kt][2] * LOG2E);
                    float p3 = exp2f(sv[kt][3] * LOG2E);
                    lpart += (p0 + p1) + (p2 + p3);
                    unsigned int lo = (unsigned int)f2bf(p0) | ((unsigned int)f2bf(p1) << 16);
                    unsigned int hi = (unsigned int)f2bf(p2) | ((unsigned int)f2bf(p3) << 16);
                    unsigned long long w = ((unsigned long long)hi << 32) | lo;
                    *(unsigned long long*)&P[wave][l16 * 72 + kt * 16 + quad * 4] = w;
                }
#pragma unroll
                for (int kc = 0; kc < 2; kc++) {
                    const short8 pf = *(const short8*)&P[wave][l16 * 72 + kc * 32 + quad * 8];
#pragma unroll
                    for (int ot = 0; ot < 4; ot++) {
                        const short8 vf = *(const short8*)&Vl[(ot * 16 + l16) * 264 + kbase + kc * 32 + quad * 8];
                        o[ot] = __builtin_amdgcn_mfma_f32_16x16x32_bf16(pf, vf, o[ot], 0, 0, 0);
                    }
                }
            }
        }
    }

    lpart += __shfl_xor(lpart, 16);
    lpart += __shfl_xor(lpart, 32);
    __syncthreads();
#pragma unroll
    for (int r = 0; r < 4; r++)
#pragma unroll
        for (int ot = 0; ot < 4; ot++)
            Of[wave * 1088 + (quad * 4 + r) * 68 + ot * 16 + l16] = o[ot][r];
    if (lane < 16) Ll[wave][lane] = lpart;
    __syncthreads();

    {
        const int row = tid >> 4;           // 0..15
        const int c0  = (tid & 15) * 4;
#pragma unroll
        for (int q2 = 0; q2 < 2; q2++) {
            // merge waves q2 and q2+2 (same q-tile, two key-halves)
            const float lsum = Ll[q2][row] + Ll[q2 + 2][row];
            float4v v0 = *(const float4v*)&Of[q2 * 1088 + row * 68 + c0];
            float4v v1 = *(const float4v*)&Of[(q2 + 2) * 1088 + row * 68 + c0];
            float4v res;
            const float inv = 1.0f / lsum;
#pragma unroll
            for (int j = 0; j < 4; j++)
                res[j] = (v0[j] + v1[j]) * inv;
            float* ob = out + (size_t)b * 131072 + (size_t)(t0 + q2 * 16 + row) * 64 + c0;
            *(float4v*)ob = res;
        }
    }
}

// ---------------------------------------------------------------------------
extern "C" void kernel_launch(void* const* d_in, const int* in_sizes, int n_in,
                              void* d_out, int out_size, void* d_ws, size_t ws_size,
                              hipStream_t stream) {
    const float* x  = (const float*)d_in[0];
    const float* Wk = (const float*)d_in[1];
    const float* Wq = (const float*)d_in[2];
    const float* Wv = (const float*)d_in[3];
    float* out = (float*)d_out;

    // Workspace: Wb 384 KB (+pad) | qs 2 MB | ks 2 MB | vT 2 MB
    unsigned short* Wb  = (unsigned short*)d_ws;
    unsigned short* qsb = (unsigned short*)((char*)d_ws + 393216);
    unsigned short* ksb = qsb + 1048576;
    unsigned short* vTb = ksb + 1048576;

    hipLaunchKernelGGL(wconv_kernel, dim3(768), dim3(256), 0, stream, Wk, Wq, Wv, Wb);
    hipLaunchKernelGGL(proj_kernel, dim3(512), dim3(256), 0, stream, x, Wb, qsb, ksb, vTb);
    hipLaunchKernelGGL(attn_kernel, dim3(512), dim3(256), 0, stream, qsb, ksb, vTb, out);
}